// Round 5
// baseline (209.366 us; speedup 1.0000x reference)
//
#include <hip/hip_runtime.h>

#define HH 20
#define WW 20

typedef __bf16  bf16x8 __attribute__((ext_vector_type(8)));
typedef float   f32x4  __attribute__((ext_vector_type(4)));
typedef float   f32x4u __attribute__((ext_vector_type(4), aligned(4)));

// ---- prepack W: k' = r*8 + ni reorder, hi/lo split, K padded 72->96 ----
// ws: Bh[256][96] bf16, Bl[256][96] bf16
__global__ void prepack_w_kernel(const float* __restrict__ Wt, __bf16* __restrict__ bp) {
    int idx = blockIdx.x * 256 + threadIdx.x;     // 24576 total
    int oc = idx / 96, k = idx % 96;
    int r = k >> 3, ni = k & 7;
    float v = (r < 9) ? Wt[oc * 72 + ni * 9 + r] : 0.f;
    __bf16 hi = (__bf16)v;
    bp[idx]         = hi;
    bp[24576 + idx] = (__bf16)(v - (float)hi);
}

// ---- fused conv + routing ----
// region (18432 B) lifetimes:
//   phase1 stage/conv : A_hi[32][96], A_lo[32][96] bf16   (12288 B)
//   phase2 transpose  : per-wave buf f32[32][36] at Rf + wv*1152 (4*4608 B)
//   phase3 routing    : route_T f32[32][36] @Rf, act_lds @Rf+1152, logits f32[32][37] @Rf+1416
__global__ __launch_bounds__(256, 8)
void caps_mfma4_kernel(const float* __restrict__ x,
                       const __bf16* __restrict__ bp,
                       const float* __restrict__ bias,
                       float* __restrict__ out) {
    __shared__ __align__(16) unsigned char region[18432];
    __bf16* A_hi = (__bf16*)region;                     // [32][96]
    __bf16* A_lo = (__bf16*)(region + 6144);            // [32][96]
    float*  Rf   = (float*)region;
    float*  act_lds = Rf + 1152;                        // [256]
    float (*logits)[37]  = (float (*)[37])(Rf + 1416);  // [32][37]
    float (*route_T)[36] = (float (*)[36])Rf;           // [co][ci]

    const int t  = threadIdx.x;
    const int wv = t >> 6;
    const int lr = t & 15;
    const int lg = (t >> 4) & 3;

    // identity mapping (round-4 XCD swizzle tripled HBM traffic -> reverted)
    const int bi  = blockIdx.x;
    const int b   = bi / 400;
    const int rem = bi % 400;
    const int h   = rem / 20;
    const int w   = rem % 20;

    // ---- zero k' pad [72,96): 12 u32 per ci per array ----
#pragma unroll
    for (int e = t; e < 384; e += 256) {
        int ci = e / 12, j = e % 12;
        ((unsigned int*)(A_hi + ci * 96 + 72))[j] = 0u;
        ((unsigned int*)(A_lo + ci * 96 + 72))[j] = 0u;
    }

    // ---- stage x patch (split bf16), k' = (hr*3+kw)*8 + ni ----
    const int wlo    = min(max(w - 1, 0), WW - 4);
    const int dshift = (w - 1) - wlo;
#pragma unroll
    for (int s = t; s < 768; s += 256) {               // (ci, ni, hr)
        int ci = s / 24;
        int r  = s % 24;
        int ni = r / 3, hr = r % 3;
        int hh = h - 1 + hr;
        bool hok = (hh >= 0) && (hh < HH);
        const float* rowp = x + ((((b * 32 + ci) * 8 + ni) * HH + (hok ? hh : 0)) * WW) + wlo;
        f32x4u f4 = *(const f32x4u*)rowp;
        int kb = hr * 24 + ni;
#pragma unroll
        for (int kw = 0; kw < 3; ++kw) {
            int ww = w - 1 + kw;
            int j  = kw + dshift;
            float v = 0.f;
            if (hok && ww >= 0 && ww < WW)
                v = (j == 0) ? f4.x : (j == 1) ? f4.y : (j == 2) ? f4.z : f4.w;
            __bf16 hi = (__bf16)v;
            A_hi[ci * 96 + kb + kw * 8] = hi;
            A_lo[ci * 96 + kb + kw * 8] = (__bf16)(v - (float)hi);
        }
    }
    __syncthreads();                                    // (1) stage -> conv

    // ---- conv via MFMA: votes = Ah*Bh + Al*Bh + Ah*Bl (M=32, N=256, K=96) ----
    const __bf16* Bh = bp;
    const __bf16* Bl = bp + 24576;
    f32x4 acc[4][2];
#pragma unroll
    for (int i = 0; i < 4; ++i)
#pragma unroll
        for (int m = 0; m < 2; ++m) acc[i][m] = (f32x4){0.f, 0.f, 0.f, 0.f};

#pragma unroll
    for (int kst = 0; kst < 3; ++kst) {
        const int kb = kst * 32 + lg * 8;
        bf16x8 a_h0 = *(const bf16x8*)&A_hi[lr * 96 + kb];
        bf16x8 a_h1 = *(const bf16x8*)&A_hi[(16 + lr) * 96 + kb];
        bf16x8 a_l0 = *(const bf16x8*)&A_lo[lr * 96 + kb];
        bf16x8 a_l1 = *(const bf16x8*)&A_lo[(16 + lr) * 96 + kb];
#pragma unroll
        for (int i = 0; i < 4; ++i) {
            const int oc = (wv * 4 + i) * 16 + lr;
            bf16x8 bh = *(const bf16x8*)&Bh[oc * 96 + kb];
            bf16x8 bl = *(const bf16x8*)&Bl[oc * 96 + kb];
            acc[i][0] = __builtin_amdgcn_mfma_f32_16x16x32_bf16(a_h0, bh, acc[i][0], 0, 0, 0);
            acc[i][1] = __builtin_amdgcn_mfma_f32_16x16x32_bf16(a_h1, bh, acc[i][1], 0, 0, 0);
            acc[i][0] = __builtin_amdgcn_mfma_f32_16x16x32_bf16(a_l0, bh, acc[i][0], 0, 0, 0);
            acc[i][1] = __builtin_amdgcn_mfma_f32_16x16x32_bf16(a_l1, bh, acc[i][1], 0, 0, 0);
            acc[i][0] = __builtin_amdgcn_mfma_f32_16x16x32_bf16(a_h0, bl, acc[i][0], 0, 0, 0);
            acc[i][1] = __builtin_amdgcn_mfma_f32_16x16x32_bf16(a_h1, bl, acc[i][1], 0, 0, 0);
        }
    }
    __syncthreads();                                    // (2) A dead -> wave bufs

    // ---- wave-local transpose: no internal barriers (same-wave LDS order) ----
    float* buf = Rf + wv * 1152;                        // f32[32][36]
    float vcol[32];                                     // votes[ci][oc=t]
    f32x4 vr[4][2];                                     // votes[no*4+q][co*8 .. +7]
    const int sub  = (t >> 5) & 1;
    const int colr = t & 31;
    const int c8   = ((t >> 3) & 3) * 8;

#pragma unroll
    for (int i = 0; i < 2; ++i)
#pragma unroll
        for (int m = 0; m < 2; ++m)
#pragma unroll
            for (int r = 0; r < 4; ++r)
                buf[(m * 16 + lg * 4 + r) * 36 + i * 16 + lr] = acc[i][m][r];
    if (sub == 0) {
#pragma unroll
        for (int ci = 0; ci < 32; ++ci) vcol[ci] = buf[ci * 36 + colr];
#pragma unroll
        for (int q = 0; q < 4; ++q) {
            int ci = (t & 7) * 4 + q;
            vr[q][0] = *(const f32x4*)&buf[ci * 36 + c8];
            vr[q][1] = *(const f32x4*)&buf[ci * 36 + c8 + 4];
        }
    }
#pragma unroll
    for (int i = 2; i < 4; ++i)
#pragma unroll
        for (int m = 0; m < 2; ++m)
#pragma unroll
            for (int r = 0; r < 4; ++r)
                buf[(m * 16 + lg * 4 + r) * 36 + (i - 2) * 16 + lr] = acc[i][m][r];
    if (sub == 1) {
#pragma unroll
        for (int ci = 0; ci < 32; ++ci) vcol[ci] = buf[ci * 36 + colr];
#pragma unroll
        for (int q = 0; q < 4; ++q) {
            int ci = (t & 7) * 4 + q;
            vr[q][0] = *(const f32x4*)&buf[ci * 36 + c8];
            vr[q][1] = *(const f32x4*)&buf[ci * 36 + c8 + 4];
        }
    }
    __syncthreads();                                    // (3) bufs dead -> routing region

    // ---- routing: thread owns oc=t (co=t>>3, no=t&7) ----
    const int co = t >> 3;
    const int no = t & 7;
    const float bsv = bias[t];
    float dlog[4];
    float act;

    // iter 1: route uniform (softmax of zeros)
    {
        float p = 0.f;
#pragma unroll
        for (int ci = 0; ci < 32; ++ci) p += vcol[ci];
        p = fmaf(p, 0.03125f, bsv);
        float n2 = p * p;
        n2 += __shfl_xor(n2, 1); n2 += __shfl_xor(n2, 2); n2 += __shfl_xor(n2, 4);
        act = p * (n2 / ((1.f + n2) * sqrtf(n2 + 1e-9f)));
        act_lds[t] = act;
    }
    __syncthreads();                                    // (4) act visible
    {
        f32x4 a0 = *(const f32x4*)&act_lds[co * 8];
        f32x4 a1 = *(const f32x4*)&act_lds[co * 8 + 4];
#pragma unroll
        for (int q = 0; q < 4; ++q) {
            f32x4 v0 = vr[q][0], v1 = vr[q][1];
            float d = v0.x * a0.x + v0.y * a0.y + v0.z * a0.z + v0.w * a0.w
                    + v1.x * a1.x + v1.y * a1.y + v1.z * a1.z + v1.w * a1.w;
            dlog[q] = d;
            logits[no * 4 + q][co] = d;
        }
    }
    __syncthreads();                                    // (5) logits -> softmax

    // iters 2..3
#pragma unroll
    for (int it = 1; it < 3; ++it) {
        {
            float l0 = logits[co][no],      l1 = logits[co][no + 8];
            float l2 = logits[co][no + 16], l3 = logits[co][no + 24];
            float m = fmaxf(fmaxf(l0, l1), fmaxf(l2, l3));
            m = fmaxf(m, __shfl_xor(m, 1)); m = fmaxf(m, __shfl_xor(m, 2)); m = fmaxf(m, __shfl_xor(m, 4));
            float e0 = __expf(l0 - m), e1 = __expf(l1 - m);
            float e2 = __expf(l2 - m), e3 = __expf(l3 - m);
            float s = e0 + e1 + e2 + e3;
            s += __shfl_xor(s, 1); s += __shfl_xor(s, 2); s += __shfl_xor(s, 4);
            float inv = 1.f / s;
            route_T[no][co]      = e0 * inv;
            route_T[no + 8][co]  = e1 * inv;
            route_T[no + 16][co] = e2 * inv;
            route_T[no + 24][co] = e3 * inv;
        }
        __syncthreads();                                // (6/8) route -> preact

        float p = bsv;
#pragma unroll
        for (int j = 0; j < 8; ++j) {
            f32x4 rv = *(const f32x4*)&route_T[co][j * 4];
            p = fmaf(rv.x, vcol[j * 4 + 0], p);
            p = fmaf(rv.y, vcol[j * 4 + 1], p);
            p = fmaf(rv.z, vcol[j * 4 + 2], p);
            p = fmaf(rv.w, vcol[j * 4 + 3], p);
        }
        float n2 = p * p;
        n2 += __shfl_xor(n2, 1); n2 += __shfl_xor(n2, 2); n2 += __shfl_xor(n2, 4);
        act = p * (n2 / ((1.f + n2) * sqrtf(n2 + 1e-9f)));

        if (it == 1) {
            act_lds[t] = act;
            __syncthreads();                            // (7) act visible
            f32x4 a0 = *(const f32x4*)&act_lds[co * 8];
            f32x4 a1 = *(const f32x4*)&act_lds[co * 8 + 4];
#pragma unroll
            for (int q = 0; q < 4; ++q) {
                f32x4 v0 = vr[q][0], v1 = vr[q][1];
                float d = v0.x * a0.x + v0.y * a0.y + v0.z * a0.z + v0.w * a0.w
                        + v1.x * a1.x + v1.y * a1.y + v1.z * a1.z + v1.w * a1.w;
                dlog[q] += d;
                logits[no * 4 + q][co] = dlog[q];
            }
            __syncthreads();                            // (8) logits -> softmax
        }
    }

    // ---- out[b][oc=t][h][w] ----
    out[(b * 256 + t) * 400 + h * 20 + w] = act;
}

extern "C" void kernel_launch(void* const* d_in, const int* in_sizes, int n_in,
                              void* d_out, int out_size, void* d_ws, size_t ws_size,
                              hipStream_t stream) {
    const float* x    = (const float*)d_in[0];
    const float* Wt   = (const float*)d_in[1];
    const float* bias = (const float*)d_in[2];
    float* out        = (float*)d_out;
    __bf16* bp        = (__bf16*)d_ws;

    prepack_w_kernel<<<dim3(96), dim3(256), 0, stream>>>(Wt, bp);
    caps_mfma4_kernel<<<dim3(16 * HH * WW), dim3(256), 0, stream>>>(x, bp, bias, out);
}

// Round 6
// 87.246 us; speedup vs baseline: 2.3997x; 2.3997x over previous
//
#include <hip/hip_runtime.h>

#define HH 20
#define WW 20

typedef __bf16  bf16x8 __attribute__((ext_vector_type(8)));
typedef float   f32x4  __attribute__((ext_vector_type(4)));
typedef float   f32x4u __attribute__((ext_vector_type(4), aligned(4)));

// ---- prepack W: k' = r*8 + ni reorder, hi/lo split, K padded 72->96 ----
// ws: Bh[256][96] bf16, Bl[256][96] bf16
__global__ void prepack_w_kernel(const float* __restrict__ Wt, __bf16* __restrict__ bp) {
    int idx = blockIdx.x * 256 + threadIdx.x;     // 24576 total
    int oc = idx / 96, k = idx % 96;
    int r = k >> 3, ni = k & 7;
    float v = (r < 9) ? Wt[oc * 72 + ni * 9 + r] : 0.f;
    __bf16 hi = (__bf16)v;
    bp[idx]         = hi;
    bp[24576 + idx] = (__bf16)(v - (float)hi);
}

// ---- fused conv + routing ----
// region (18432 B) lifetimes:
//   phase1 stage/conv : A_hi[32][96], A_lo[32][96] bf16   (12288 B)
//   phase2 transpose  : per-wave buf f32[32][36] at Rf + wv*1152 (4*4608 B)
//   phase3 routing    : route_T f32[32][36] @Rf, act_lds @Rf+1152, logits f32[32][37] @Rf+1416
// launch_bounds(256,4): 128-VGPR cap. Live state ~88 regs (acc32+vcol32+vr8+temps)
// -- (256,8) in round 5 capped at 64 and spilled to scratch (WRITE_SIZE 487 MB).
__global__ __launch_bounds__(256, 4)
void caps_mfma5_kernel(const float* __restrict__ x,
                       const __bf16* __restrict__ bp,
                       const float* __restrict__ bias,
                       float* __restrict__ out) {
    __shared__ __align__(16) unsigned char region[18432];
    __bf16* A_hi = (__bf16*)region;                     // [32][96]
    __bf16* A_lo = (__bf16*)(region + 6144);            // [32][96]
    float*  Rf   = (float*)region;
    float*  act_lds = Rf + 1152;                        // [256]
    float (*logits)[37]  = (float (*)[37])(Rf + 1416);  // [32][37]
    float (*route_T)[36] = (float (*)[36])Rf;           // [co][ci]

    const int t  = threadIdx.x;
    const int wv = t >> 6;
    const int lr = t & 15;
    const int lg = (t >> 4) & 3;

    const int bi  = blockIdx.x;
    const int b   = bi / 400;
    const int rem = bi % 400;
    const int h   = rem / 20;
    const int w   = rem % 20;

    // ---- zero k' pad [72,96): 12 u32 per ci per array ----
#pragma unroll
    for (int e = t; e < 384; e += 256) {
        int ci = e / 12, j = e % 12;
        ((unsigned int*)(A_hi + ci * 96 + 72))[j] = 0u;
        ((unsigned int*)(A_lo + ci * 96 + 72))[j] = 0u;
    }

    // ---- stage x patch (split bf16), k' = (hr*3+kw)*8 + ni ----
    const int wlo    = min(max(w - 1, 0), WW - 4);
    const int dshift = (w - 1) - wlo;
#pragma unroll
    for (int s = t; s < 768; s += 256) {               // (ci, ni, hr)
        int ci = s / 24;
        int r  = s % 24;
        int ni = r / 3, hr = r % 3;
        int hh = h - 1 + hr;
        bool hok = (hh >= 0) && (hh < HH);
        const float* rowp = x + ((((b * 32 + ci) * 8 + ni) * HH + (hok ? hh : 0)) * WW) + wlo;
        f32x4u f4 = *(const f32x4u*)rowp;
        int kb = hr * 24 + ni;
#pragma unroll
        for (int kw = 0; kw < 3; ++kw) {
            int ww = w - 1 + kw;
            int j  = kw + dshift;
            float v = 0.f;
            if (hok && ww >= 0 && ww < WW)
                v = (j == 0) ? f4.x : (j == 1) ? f4.y : (j == 2) ? f4.z : f4.w;
            __bf16 hi = (__bf16)v;
            A_hi[ci * 96 + kb + kw * 8] = hi;
            A_lo[ci * 96 + kb + kw * 8] = (__bf16)(v - (float)hi);
        }
    }
    __syncthreads();                                    // (1) stage -> conv

    // ---- conv via MFMA: votes = Ah*Bh + Al*Bh + Ah*Bl (M=32, N=256, K=96) ----
    const __bf16* Bh = bp;
    const __bf16* Bl = bp + 24576;
    f32x4 acc[4][2];
#pragma unroll
    for (int i = 0; i < 4; ++i)
#pragma unroll
        for (int m = 0; m < 2; ++m) acc[i][m] = (f32x4){0.f, 0.f, 0.f, 0.f};

#pragma unroll
    for (int kst = 0; kst < 3; ++kst) {
        const int kb = kst * 32 + lg * 8;
        bf16x8 a_h0 = *(const bf16x8*)&A_hi[lr * 96 + kb];
        bf16x8 a_h1 = *(const bf16x8*)&A_hi[(16 + lr) * 96 + kb];
        bf16x8 a_l0 = *(const bf16x8*)&A_lo[lr * 96 + kb];
        bf16x8 a_l1 = *(const bf16x8*)&A_lo[(16 + lr) * 96 + kb];
#pragma unroll
        for (int i = 0; i < 4; ++i) {
            const int oc = (wv * 4 + i) * 16 + lr;
            bf16x8 bh = *(const bf16x8*)&Bh[oc * 96 + kb];
            bf16x8 bl = *(const bf16x8*)&Bl[oc * 96 + kb];
            acc[i][0] = __builtin_amdgcn_mfma_f32_16x16x32_bf16(a_h0, bh, acc[i][0], 0, 0, 0);
            acc[i][1] = __builtin_amdgcn_mfma_f32_16x16x32_bf16(a_h1, bh, acc[i][1], 0, 0, 0);
            acc[i][0] = __builtin_amdgcn_mfma_f32_16x16x32_bf16(a_l0, bh, acc[i][0], 0, 0, 0);
            acc[i][1] = __builtin_amdgcn_mfma_f32_16x16x32_bf16(a_l1, bh, acc[i][1], 0, 0, 0);
            acc[i][0] = __builtin_amdgcn_mfma_f32_16x16x32_bf16(a_h0, bl, acc[i][0], 0, 0, 0);
            acc[i][1] = __builtin_amdgcn_mfma_f32_16x16x32_bf16(a_h1, bl, acc[i][1], 0, 0, 0);
        }
    }
    __syncthreads();                                    // (2) A dead -> wave bufs

    // ---- wave-local transpose: no internal barriers (same-wave LDS order) ----
    float* buf = Rf + wv * 1152;                        // f32[32][36]
    float vcol[32];                                     // votes[ci][oc=t]
    f32x4 vr[4][2];                                     // votes[no*4+q][co*8 .. +7]
    const int sub  = (t >> 5) & 1;
    const int colr = t & 31;
    const int c8   = ((t >> 3) & 3) * 8;

#pragma unroll
    for (int i = 0; i < 2; ++i)
#pragma unroll
        for (int m = 0; m < 2; ++m)
#pragma unroll
            for (int r = 0; r < 4; ++r)
                buf[(m * 16 + lg * 4 + r) * 36 + i * 16 + lr] = acc[i][m][r];
    if (sub == 0) {
#pragma unroll
        for (int ci = 0; ci < 32; ++ci) vcol[ci] = buf[ci * 36 + colr];
#pragma unroll
        for (int q = 0; q < 4; ++q) {
            int ci = (t & 7) * 4 + q;
            vr[q][0] = *(const f32x4*)&buf[ci * 36 + c8];
            vr[q][1] = *(const f32x4*)&buf[ci * 36 + c8 + 4];
        }
    }
#pragma unroll
    for (int i = 2; i < 4; ++i)
#pragma unroll
        for (int m = 0; m < 2; ++m)
#pragma unroll
            for (int r = 0; r < 4; ++r)
                buf[(m * 16 + lg * 4 + r) * 36 + (i - 2) * 16 + lr] = acc[i][m][r];
    if (sub == 1) {
#pragma unroll
        for (int ci = 0; ci < 32; ++ci) vcol[ci] = buf[ci * 36 + colr];
#pragma unroll
        for (int q = 0; q < 4; ++q) {
            int ci = (t & 7) * 4 + q;
            vr[q][0] = *(const f32x4*)&buf[ci * 36 + c8];
            vr[q][1] = *(const f32x4*)&buf[ci * 36 + c8 + 4];
        }
    }
    __syncthreads();                                    // (3) bufs dead -> routing region

    // ---- routing: thread owns oc=t (co=t>>3, no=t&7) ----
    const int co = t >> 3;
    const int no = t & 7;
    const float bsv = bias[t];
    float dlog[4];
    float act;

    // iter 1: route uniform (softmax of zeros)
    {
        float p = 0.f;
#pragma unroll
        for (int ci = 0; ci < 32; ++ci) p += vcol[ci];
        p = fmaf(p, 0.03125f, bsv);
        float n2 = p * p;
        n2 += __shfl_xor(n2, 1); n2 += __shfl_xor(n2, 2); n2 += __shfl_xor(n2, 4);
        act = p * (n2 / ((1.f + n2) * sqrtf(n2 + 1e-9f)));
        act_lds[t] = act;
    }
    __syncthreads();                                    // (4) act visible
    {
        f32x4 a0 = *(const f32x4*)&act_lds[co * 8];
        f32x4 a1 = *(const f32x4*)&act_lds[co * 8 + 4];
#pragma unroll
        for (int q = 0; q < 4; ++q) {
            f32x4 v0 = vr[q][0], v1 = vr[q][1];
            float d = v0.x * a0.x + v0.y * a0.y + v0.z * a0.z + v0.w * a0.w
                    + v1.x * a1.x + v1.y * a1.y + v1.z * a1.z + v1.w * a1.w;
            dlog[q] = d;
            logits[no * 4 + q][co] = d;
        }
    }
    __syncthreads();                                    // (5) logits -> softmax

    // iters 2..3
#pragma unroll
    for (int it = 1; it < 3; ++it) {
        {
            float l0 = logits[co][no],      l1 = logits[co][no + 8];
            float l2 = logits[co][no + 16], l3 = logits[co][no + 24];
            float m = fmaxf(fmaxf(l0, l1), fmaxf(l2, l3));
            m = fmaxf(m, __shfl_xor(m, 1)); m = fmaxf(m, __shfl_xor(m, 2)); m = fmaxf(m, __shfl_xor(m, 4));
            float e0 = __expf(l0 - m), e1 = __expf(l1 - m);
            float e2 = __expf(l2 - m), e3 = __expf(l3 - m);
            float s = e0 + e1 + e2 + e3;
            s += __shfl_xor(s, 1); s += __shfl_xor(s, 2); s += __shfl_xor(s, 4);
            float inv = 1.f / s;
            route_T[no][co]      = e0 * inv;
            route_T[no + 8][co]  = e1 * inv;
            route_T[no + 16][co] = e2 * inv;
            route_T[no + 24][co] = e3 * inv;
        }
        __syncthreads();                                // (6/8) route -> preact

        float p = bsv;
#pragma unroll
        for (int j = 0; j < 8; ++j) {
            f32x4 rv = *(const f32x4*)&route_T[co][j * 4];
            p = fmaf(rv.x, vcol[j * 4 + 0], p);
            p = fmaf(rv.y, vcol[j * 4 + 1], p);
            p = fmaf(rv.z, vcol[j * 4 + 2], p);
            p = fmaf(rv.w, vcol[j * 4 + 3], p);
        }
        float n2 = p * p;
        n2 += __shfl_xor(n2, 1); n2 += __shfl_xor(n2, 2); n2 += __shfl_xor(n2, 4);
        act = p * (n2 / ((1.f + n2) * sqrtf(n2 + 1e-9f)));

        if (it == 1) {
            act_lds[t] = act;
            __syncthreads();                            // (7) act visible
            f32x4 a0 = *(const f32x4*)&act_lds[co * 8];
            f32x4 a1 = *(const f32x4*)&act_lds[co * 8 + 4];
#pragma unroll
            for (int q = 0; q < 4; ++q) {
                f32x4 v0 = vr[q][0], v1 = vr[q][1];
                float d = v0.x * a0.x + v0.y * a0.y + v0.z * a0.z + v0.w * a0.w
                        + v1.x * a1.x + v1.y * a1.y + v1.z * a1.z + v1.w * a1.w;
                dlog[q] += d;
                logits[no * 4 + q][co] = dlog[q];
            }
            __syncthreads();                            // (8) logits -> softmax
        }
    }

    // ---- out[b][oc=t][h][w] ----
    out[(b * 256 + t) * 400 + h * 20 + w] = act;
}

extern "C" void kernel_launch(void* const* d_in, const int* in_sizes, int n_in,
                              void* d_out, int out_size, void* d_ws, size_t ws_size,
                              hipStream_t stream) {
    const float* x    = (const float*)d_in[0];
    const float* Wt   = (const float*)d_in[1];
    const float* bias = (const float*)d_in[2];
    float* out        = (float*)d_out;
    __bf16* bp        = (__bf16*)d_ws;

    prepack_w_kernel<<<dim3(96), dim3(256), 0, stream>>>(Wt, bp);
    caps_mfma5_kernel<<<dim3(16 * HH * WW), dim3(256), 0, stream>>>(x, bp, bias, out);
}

// Round 7
// 74.073 us; speedup vs baseline: 2.8265x; 1.1778x over previous
//
#include <hip/hip_runtime.h>

#define HH 20
#define WW 20

typedef __bf16  bf16x8 __attribute__((ext_vector_type(8)));
typedef float   f32x4  __attribute__((ext_vector_type(4)));
typedef float   f32x4u __attribute__((ext_vector_type(4), aligned(4)));

// ---- prepack W: k' = r*8 + ni reorder, hi/lo split, K padded 72->96 ----
__global__ void prepack_w_kernel(const float* __restrict__ Wt, __bf16* __restrict__ bp) {
    int idx = blockIdx.x * 256 + threadIdx.x;     // 24576 total
    int oc = idx / 96, k = idx % 96;
    int r = k >> 3, ni = k & 7;
    float v = (r < 9) ? Wt[oc * 72 + ni * 9 + r] : 0.f;
    __bf16 hi = (__bf16)v;
    bp[idx]         = hi;
    bp[24576 + idx] = (__bf16)(v - (float)hi);
}

// ---- fused conv + routing, TWO adjacent pixels (w0, w0+1) per block ----
// region (24576 B) lifetimes:
//   phase1 stage/conv : A_hi[64][96], A_lo[64][96] bf16 (rows 0-31 = px0, 32-63 = px1)
//   phase2 transpose  : per-wave buf f32[32][36] at Rf + wv*1152 (18432 B), 4 sub-rounds
//   phase3 routing    : route_T[2][32][36] @Rf, act[2][256] @Rf+2304, logits[2][32][37] @Rf+2816
// launch_bounds(256,3): 170-VGPR cap — live state ~150 (vcol 64 + vr 16 + acc 64 tail);
// (256,4)=128 cap risks the round-5 spill disaster.
__global__ __launch_bounds__(256, 3)
void caps_mfma6_kernel(const float* __restrict__ x,
                       const __bf16* __restrict__ bp,
                       const float* __restrict__ bias,
                       float* __restrict__ out) {
    __shared__ __align__(16) unsigned char region[24576];
    __bf16* A_hi = (__bf16*)region;                     // [64][96]
    __bf16* A_lo = (__bf16*)(region + 12288);           // [64][96]
    float*  Rf   = (float*)region;

    const int t  = threadIdx.x;
    const int wv = t >> 6;
    const int lr = t & 15;
    const int lg = (t >> 4) & 3;

    const int bi  = blockIdx.x;            // 3200 blocks
    const int b   = bi / 200;
    const int rem = bi % 200;
    const int h   = rem / 10;
    const int w0  = (rem % 10) * 2;

    // ---- zero k' pad [72,96): 64 rows * 12 u32 each array ----
#pragma unroll
    for (int e = t; e < 768; e += 256) {
        int row = e / 12, j = e % 12;
        ((unsigned int*)(A_hi + row * 96 + 72))[j] = 0u;
        ((unsigned int*)(A_lo + row * 96 + 72))[j] = 0u;
    }

    // ---- stage x window cols w0-1..w0+2 (serves both pixels), k'=(hr*3+kw)*8+ni ----
    const int wlo    = min(max(w0 - 1, 0), WW - 4);
    const int dshift = (w0 - 1) - wlo;                  // -1, 0, or +1
#pragma unroll
    for (int s = t; s < 768; s += 256) {                // (ci, ni, hr)
        int ci = s / 24;
        int r  = s % 24;
        int ni = r / 3, hr = r % 3;
        int hh = h - 1 + hr;
        bool hok = (hh >= 0) && (hh < HH);
        const float* rowp = x + ((((b * 32 + ci) * 8 + ni) * HH + (hok ? hh : 0)) * WW) + wlo;
        f32x4u f4 = *(const f32x4u*)rowp;
        int kb = hr * 24 + ni;
#pragma unroll
        for (int j = 0; j < 4; ++j) {                   // window col c = w0-1+j
            int c   = w0 - 1 + j;
            int idx = j + dshift;
            float v = 0.f;
            if (hok && c >= 0 && c < WW)
                v = (idx == 0) ? f4.x : (idx == 1) ? f4.y : (idx == 2) ? f4.z : f4.w;
            __bf16 hi = (__bf16)v;
            __bf16 lo = (__bf16)(v - (float)hi);
            if (j < 3) {                                // px0, kw=j
                A_hi[ci * 96 + kb + j * 8] = hi;
                A_lo[ci * 96 + kb + j * 8] = lo;
            }
            if (j > 0) {                                // px1, kw=j-1
                A_hi[(32 + ci) * 96 + kb + (j - 1) * 8] = hi;
                A_lo[(32 + ci) * 96 + kb + (j - 1) * 8] = lo;
            }
        }
    }
    __syncthreads();                                    // (1) stage -> conv

    // ---- conv via MFMA: M=64, N=256, K=96; votes = Ah*Bh + Al*Bh + Ah*Bl ----
    const __bf16* Bh = bp;
    const __bf16* Bl = bp + 24576;
    f32x4 acc[4][4];                                    // [N-tile i][M-tile mt]
#pragma unroll
    for (int i = 0; i < 4; ++i)
#pragma unroll
        for (int mt = 0; mt < 4; ++mt) acc[i][mt] = (f32x4){0.f, 0.f, 0.f, 0.f};

#pragma unroll
    for (int mh = 0; mh < 2; ++mh) {                    // M-half = pixel
#pragma unroll
        for (int kst = 0; kst < 3; ++kst) {
            const int kb = kst * 32 + lg * 8;
            bf16x8 ah0 = *(const bf16x8*)&A_hi[(mh * 32 + lr) * 96 + kb];
            bf16x8 ah1 = *(const bf16x8*)&A_hi[(mh * 32 + 16 + lr) * 96 + kb];
            bf16x8 al0 = *(const bf16x8*)&A_lo[(mh * 32 + lr) * 96 + kb];
            bf16x8 al1 = *(const bf16x8*)&A_lo[(mh * 32 + 16 + lr) * 96 + kb];
#pragma unroll
            for (int i = 0; i < 4; ++i) {
                const int oc = (wv * 4 + i) * 16 + lr;
                bf16x8 bh = *(const bf16x8*)&Bh[oc * 96 + kb];
                bf16x8 bl = *(const bf16x8*)&Bl[oc * 96 + kb];
                acc[i][mh*2+0] = __builtin_amdgcn_mfma_f32_16x16x32_bf16(ah0, bh, acc[i][mh*2+0], 0, 0, 0);
                acc[i][mh*2+1] = __builtin_amdgcn_mfma_f32_16x16x32_bf16(ah1, bh, acc[i][mh*2+1], 0, 0, 0);
                acc[i][mh*2+0] = __builtin_amdgcn_mfma_f32_16x16x32_bf16(al0, bh, acc[i][mh*2+0], 0, 0, 0);
                acc[i][mh*2+1] = __builtin_amdgcn_mfma_f32_16x16x32_bf16(al1, bh, acc[i][mh*2+1], 0, 0, 0);
                acc[i][mh*2+0] = __builtin_amdgcn_mfma_f32_16x16x32_bf16(ah0, bl, acc[i][mh*2+0], 0, 0, 0);
                acc[i][mh*2+1] = __builtin_amdgcn_mfma_f32_16x16x32_bf16(ah1, bl, acc[i][mh*2+1], 0, 0, 0);
            }
        }
    }
    __syncthreads();                                    // (2) A dead -> wave bufs

    // ---- wave-local transpose: 4 sub-rounds (pixel p x col-half ch), no barriers ----
    float* buf = Rf + wv * 1152;                        // f32[32][36]
    float vcol[2][32];                                  // [px][ci] for oc = t
    f32x4 vr[2][4][2];                                  // [px][q] votes[no*4+q][co*8..+7]
    const int ch_t = (t >> 5) & 1;
    const int colr = t & 31;
    const int c8   = t & 24;

#pragma unroll
    for (int p = 0; p < 2; ++p) {
#pragma unroll
        for (int ch = 0; ch < 2; ++ch) {
#pragma unroll
            for (int ii = 0; ii < 2; ++ii) {
#pragma unroll
                for (int mm = 0; mm < 2; ++mm) {
#pragma unroll
                    for (int r = 0; r < 4; ++r)
                        buf[(mm * 16 + lg * 4 + r) * 36 + ii * 16 + lr] =
                            acc[ch * 2 + ii][p * 2 + mm][r];
                }
            }
            if (ch_t == ch) {
#pragma unroll
                for (int ci = 0; ci < 32; ++ci) vcol[p][ci] = buf[ci * 36 + colr];
#pragma unroll
                for (int q = 0; q < 4; ++q) {
                    int ciq = (t & 7) * 4 + q;
                    vr[p][q][0] = *(const f32x4*)&buf[ciq * 36 + c8];
                    vr[p][q][1] = *(const f32x4*)&buf[ciq * 36 + c8 + 4];
                }
            }
        }
    }
    __syncthreads();                                    // (3) bufs dead -> routing region

    // ---- routing: thread owns oc=t (co=t>>3, no=t&7) for BOTH pixels ----
    const int co = t >> 3;
    const int no = t & 7;
    const float bsv = bias[t];
    float* route0 = Rf;                                 // [32][36]  (col c major)
    float* route1 = Rf + 1152;
    float* actl   = Rf + 2304;                          // [2][256]
    float (*lg0)[37] = (float (*)[37])(Rf + 2816);
    float (*lg1)[37] = (float (*)[37])(Rf + 2816 + 1184);
    float dlog[2][4];
    float act[2];

    // iter 1: route exactly uniform
#pragma unroll
    for (int px = 0; px < 2; ++px) {
        float p = 0.f;
#pragma unroll
        for (int ci = 0; ci < 32; ++ci) p += vcol[px][ci];
        p = fmaf(p, 0.03125f, bsv);
        float n2 = p * p;
        n2 += __shfl_xor(n2, 1); n2 += __shfl_xor(n2, 2); n2 += __shfl_xor(n2, 4);
        act[px] = p * (n2 / ((1.f + n2) * sqrtf(n2 + 1e-9f)));
        actl[px * 256 + t] = act[px];
    }
    __syncthreads();                                    // (4) act visible
#pragma unroll
    for (int px = 0; px < 2; ++px) {
        f32x4 a0 = *(const f32x4*)&actl[px * 256 + co * 8];
        f32x4 a1 = *(const f32x4*)&actl[px * 256 + co * 8 + 4];
        float (*lgp)[37] = px ? lg1 : lg0;
#pragma unroll
        for (int q = 0; q < 4; ++q) {
            f32x4 v0 = vr[px][q][0], v1 = vr[px][q][1];
            float d = v0.x * a0.x + v0.y * a0.y + v0.z * a0.z + v0.w * a0.w
                    + v1.x * a1.x + v1.y * a1.y + v1.z * a1.z + v1.w * a1.w;
            dlog[px][q] = d;
            lgp[no * 4 + q][co] = d;
        }
    }
    __syncthreads();                                    // (5) logits -> softmax

    // iters 2..3
#pragma unroll
    for (int it = 1; it < 3; ++it) {
#pragma unroll
        for (int px = 0; px < 2; ++px) {                // softmax over co per ci-row
            float (*lgp)[37] = px ? lg1 : lg0;
            float* rtp = px ? route1 : route0;
            float l0 = lgp[co][no],      l1 = lgp[co][no + 8];
            float l2 = lgp[co][no + 16], l3 = lgp[co][no + 24];
            float m = fmaxf(fmaxf(l0, l1), fmaxf(l2, l3));
            m = fmaxf(m, __shfl_xor(m, 1)); m = fmaxf(m, __shfl_xor(m, 2)); m = fmaxf(m, __shfl_xor(m, 4));
            float e0 = __expf(l0 - m), e1 = __expf(l1 - m);
            float e2 = __expf(l2 - m), e3 = __expf(l3 - m);
            float s = e0 + e1 + e2 + e3;
            s += __shfl_xor(s, 1); s += __shfl_xor(s, 2); s += __shfl_xor(s, 4);
            float inv = 1.f / s;
            rtp[(no)      * 36 + co] = e0 * inv;
            rtp[(no + 8)  * 36 + co] = e1 * inv;
            rtp[(no + 16) * 36 + co] = e2 * inv;
            rtp[(no + 24) * 36 + co] = e3 * inv;
        }
        __syncthreads();                                // (6/8) route -> preact

#pragma unroll
        for (int px = 0; px < 2; ++px) {
            float* rtp = px ? route1 : route0;
            float p = bsv;
#pragma unroll
            for (int j = 0; j < 8; ++j) {
                f32x4 rv = *(const f32x4*)&rtp[co * 36 + j * 4];
                p = fmaf(rv.x, vcol[px][j * 4 + 0], p);
                p = fmaf(rv.y, vcol[px][j * 4 + 1], p);
                p = fmaf(rv.z, vcol[px][j * 4 + 2], p);
                p = fmaf(rv.w, vcol[px][j * 4 + 3], p);
            }
            float n2 = p * p;
            n2 += __shfl_xor(n2, 1); n2 += __shfl_xor(n2, 2); n2 += __shfl_xor(n2, 4);
            act[px] = p * (n2 / ((1.f + n2) * sqrtf(n2 + 1e-9f)));
        }

        if (it == 1) {
#pragma unroll
            for (int px = 0; px < 2; ++px) actl[px * 256 + t] = act[px];
            __syncthreads();                            // (7) act visible
#pragma unroll
            for (int px = 0; px < 2; ++px) {
                f32x4 a0 = *(const f32x4*)&actl[px * 256 + co * 8];
                f32x4 a1 = *(const f32x4*)&actl[px * 256 + co * 8 + 4];
                float (*lgp)[37] = px ? lg1 : lg0;
#pragma unroll
                for (int q = 0; q < 4; ++q) {
                    f32x4 v0 = vr[px][q][0], v1 = vr[px][q][1];
                    float d = v0.x * a0.x + v0.y * a0.y + v0.z * a0.z + v0.w * a0.w
                            + v1.x * a1.x + v1.y * a1.y + v1.z * a1.z + v1.w * a1.w;
                    dlog[px][q] += d;
                    lgp[no * 4 + q][co] = dlog[px][q];
                }
            }
            __syncthreads();                            // (8) logits -> softmax
        }
    }

    // ---- out[b][oc=t][h][w0..w0+1]: one float2 store ----
    float2 o2 = make_float2(act[0], act[1]);
    *(float2*)&out[(b * 256 + t) * 400 + h * 20 + w0] = o2;
}

extern "C" void kernel_launch(void* const* d_in, const int* in_sizes, int n_in,
                              void* d_out, int out_size, void* d_ws, size_t ws_size,
                              hipStream_t stream) {
    const float* x    = (const float*)d_in[0];
    const float* Wt   = (const float*)d_in[1];
    const float* bias = (const float*)d_in[2];
    float* out        = (float*)d_out;
    __bf16* bp        = (__bf16*)d_ws;

    prepack_w_kernel<<<dim3(96), dim3(256), 0, stream>>>(Wt, bp);
    caps_mfma6_kernel<<<dim3(3200), dim3(256), 0, stream>>>(x, bp, bias, out);
}

// Round 8
// 72.348 us; speedup vs baseline: 2.8939x; 1.0238x over previous
//
#include <hip/hip_runtime.h>

#define HH 20
#define WW 20

typedef __bf16  bf16x8 __attribute__((ext_vector_type(8)));
typedef float   f32x4  __attribute__((ext_vector_type(4)));
typedef float   f32x4u __attribute__((ext_vector_type(4), aligned(4)));

// ---- prepack W: k' = r*8 + ni reorder, hi/lo split, K padded 72->96 ----
__global__ void prepack_w_kernel(const float* __restrict__ Wt, __bf16* __restrict__ bp) {
    int idx = blockIdx.x * 256 + threadIdx.x;     // 24576 total
    int oc = idx / 96, k = idx % 96;
    int r = k >> 3, ni = k & 7;
    float v = (r < 9) ? Wt[oc * 72 + ni * 9 + r] : 0.f;
    __bf16 hi = (__bf16)v;
    bp[idx]         = hi;
    bp[24576 + idx] = (__bf16)(v - (float)hi);
}

// Staging helper: DS = dshift (block-uniform). Window cols w0-1..w0+2 via one f32x4.
template<int DS>
__device__ __forceinline__ void stage_seg(const float* __restrict__ x,
                                          __bf16* A_hi, __bf16* A_lo,
                                          int b, int h, int w0, int t) {
#pragma unroll
    for (int s = t; s < 768; s += 256) {               // (ci, ni, hr)
        int ci = s / 24;
        int r  = s % 24;
        int ni = r / 3, hr = r % 3;
        int hh = h - 1 + hr;
        bool hok = (hh >= 0) && (hh < HH);
        const int wlo = (DS == 0) ? (w0 - 1) : (DS < 0 ? 0 : WW - 4);
        const float* rowp = x + ((((b * 32 + ci) * 8 + ni) * HH + (hok ? hh : 0)) * WW) + wlo;
        f32x4u f4 = *(const f32x4u*)rowp;
        float vals[4];
        if (DS == 0)      { vals[0] = f4.x; vals[1] = f4.y; vals[2] = f4.z; vals[3] = f4.w; }
        else if (DS < 0)  { vals[0] = 0.f;  vals[1] = f4.x; vals[2] = f4.y; vals[3] = f4.z; }
        else              { vals[0] = f4.y; vals[1] = f4.z; vals[2] = f4.w; vals[3] = 0.f; }
        int kb = hr * 24 + ni;
#pragma unroll
        for (int j = 0; j < 4; ++j) {                  // window col c = w0-1+j
            float v = hok ? vals[j] : 0.f;
            __bf16 hi = (__bf16)v;
            __bf16 lo = (__bf16)(v - (float)hi);
            if (j < 3) {                               // px0, kw=j
                A_hi[ci * 96 + kb + j * 8] = hi;
                A_lo[ci * 96 + kb + j * 8] = lo;
            }
            if (j > 0) {                               // px1, kw=j-1
                A_hi[(32 + ci) * 96 + kb + (j - 1) * 8] = hi;
                A_lo[(32 + ci) * 96 + kb + (j - 1) * 8] = lo;
            }
        }
    }
}

// ---- fused conv + routing, TWO adjacent pixels (w0, w0+1) per block ----
// region (24576 B) lifetimes:
//   phase1 stage/conv : A_hi[64][96], A_lo[64][96] bf16
//   phase2 transpose  : per-wave buf f32[32][36] at Rf + wv*1152
//   phase3 routing    : route0/1 [32][36] @Rf/+1152, logits0/1 [32][37] @Rf+2304/+3488
// 7 block barriers (was 9: act broadcast now via intra-group shuffles).
__global__ __launch_bounds__(256, 3)
void caps_mfma7_kernel(const float* __restrict__ x,
                       const __bf16* __restrict__ bp,
                       const float* __restrict__ bias,
                       float* __restrict__ out) {
    __shared__ __align__(16) unsigned char region[24576];
    __bf16* A_hi = (__bf16*)region;                     // [64][96]
    __bf16* A_lo = (__bf16*)(region + 12288);           // [64][96]
    float*  Rf   = (float*)region;

    const int t  = threadIdx.x;
    const int wv = t >> 6;
    const int lr = t & 15;
    const int lg = (t >> 4) & 3;

    const int bi  = blockIdx.x;            // 3200 blocks
    const int b   = bi / 200;
    const int rem = bi % 200;
    const int h   = rem / 10;
    const int w0  = (rem % 10) * 2;

    // ---- zero k' pad [72,96) ----
#pragma unroll
    for (int e = t; e < 768; e += 256) {
        int row = e / 12, j = e % 12;
        ((unsigned int*)(A_hi + row * 96 + 72))[j] = 0u;
        ((unsigned int*)(A_lo + row * 96 + 72))[j] = 0u;
    }

    // ---- stage x window (block-uniform dshift branch, no divergence) ----
    const int dshift = (w0 == 0) ? -1 : (w0 == WW - 2) ? 1 : 0;
    if (dshift == 0)      stage_seg<0>(x, A_hi, A_lo, b, h, w0, t);
    else if (dshift < 0)  stage_seg<-1>(x, A_hi, A_lo, b, h, w0, t);
    else                  stage_seg<1>(x, A_hi, A_lo, b, h, w0, t);
    __syncthreads();                                    // (1) stage -> conv

    // ---- conv via MFMA: M=64, N=256, K=96; votes = Ah*Bh + Al*Bh + Ah*Bl ----
    const __bf16* Bh = bp;
    const __bf16* Bl = bp + 24576;
    f32x4 acc[4][4];                                    // [N-tile i][M-tile mt]
#pragma unroll
    for (int i = 0; i < 4; ++i)
#pragma unroll
        for (int mt = 0; mt < 4; ++mt) acc[i][mt] = (f32x4){0.f, 0.f, 0.f, 0.f};

#pragma unroll
    for (int mh = 0; mh < 2; ++mh) {                    // M-half = pixel
#pragma unroll
        for (int kst = 0; kst < 3; ++kst) {
            const int kb = kst * 32 + lg * 8;
            bf16x8 ah0 = *(const bf16x8*)&A_hi[(mh * 32 + lr) * 96 + kb];
            bf16x8 ah1 = *(const bf16x8*)&A_hi[(mh * 32 + 16 + lr) * 96 + kb];
            bf16x8 al0 = *(const bf16x8*)&A_lo[(mh * 32 + lr) * 96 + kb];
            bf16x8 al1 = *(const bf16x8*)&A_lo[(mh * 32 + 16 + lr) * 96 + kb];
#pragma unroll
            for (int i = 0; i < 4; ++i) {
                const int oc = (wv * 4 + i) * 16 + lr;
                bf16x8 bh = *(const bf16x8*)&Bh[oc * 96 + kb];
                bf16x8 bl = *(const bf16x8*)&Bl[oc * 96 + kb];
                acc[i][mh*2+0] = __builtin_amdgcn_mfma_f32_16x16x32_bf16(ah0, bh, acc[i][mh*2+0], 0, 0, 0);
                acc[i][mh*2+1] = __builtin_amdgcn_mfma_f32_16x16x32_bf16(ah1, bh, acc[i][mh*2+1], 0, 0, 0);
                acc[i][mh*2+0] = __builtin_amdgcn_mfma_f32_16x16x32_bf16(al0, bh, acc[i][mh*2+0], 0, 0, 0);
                acc[i][mh*2+1] = __builtin_amdgcn_mfma_f32_16x16x32_bf16(al1, bh, acc[i][mh*2+1], 0, 0, 0);
                acc[i][mh*2+0] = __builtin_amdgcn_mfma_f32_16x16x32_bf16(ah0, bl, acc[i][mh*2+0], 0, 0, 0);
                acc[i][mh*2+1] = __builtin_amdgcn_mfma_f32_16x16x32_bf16(ah1, bl, acc[i][mh*2+1], 0, 0, 0);
            }
        }
    }
    __syncthreads();                                    // (2) A dead -> wave bufs

    // ---- wave-local transpose: 4 sub-rounds, no internal barriers ----
    float* buf = Rf + wv * 1152;                        // f32[32][36]
    float vcol[2][32];                                  // [px][ci] for oc = t
    f32x4 vr[2][4][2];                                  // [px][q] votes[(t&7)*4+q][(t&~7)+0..7]
    const int ch_t = (t >> 5) & 1;
    const int colr = t & 31;
    const int c8   = t & 24;

#pragma unroll
    for (int p = 0; p < 2; ++p) {
#pragma unroll
        for (int ch = 0; ch < 2; ++ch) {
#pragma unroll
            for (int ii = 0; ii < 2; ++ii) {
#pragma unroll
                for (int mm = 0; mm < 2; ++mm) {
#pragma unroll
                    for (int r = 0; r < 4; ++r)
                        buf[(mm * 16 + lg * 4 + r) * 36 + ii * 16 + lr] =
                            acc[ch * 2 + ii][p * 2 + mm][r];
                }
            }
            if (ch_t == ch) {
#pragma unroll
                for (int ci = 0; ci < 32; ++ci) vcol[p][ci] = buf[ci * 36 + colr];
#pragma unroll
                for (int q = 0; q < 4; ++q) {
                    int ciq = (t & 7) * 4 + q;
                    vr[p][q][0] = *(const f32x4*)&buf[ciq * 36 + c8];
                    vr[p][q][1] = *(const f32x4*)&buf[ciq * 36 + c8 + 4];
                }
            }
        }
    }
    __syncthreads();                                    // (3) bufs dead -> routing region

    // ---- routing: thread owns oc=t (co=t>>3, no=t&7) for BOTH pixels ----
    const int co = t >> 3;
    const int no = t & 7;
    const float bsv = bias[t];
    float* route0 = Rf;                                 // [32][36]
    float* route1 = Rf + 1152;
    float (*lg0)[37] = (float (*)[37])(Rf + 2304);
    float (*lg1)[37] = (float (*)[37])(Rf + 2304 + 1184);
    float dlog[2][4];
    float act[2];
    const int lbase = t & 56;                           // lane base of 8-lane co-group

    // iter 1: route exactly uniform; act broadcast via intra-group shuffles
#pragma unroll
    for (int px = 0; px < 2; ++px) {
        float p = 0.f;
#pragma unroll
        for (int ci = 0; ci < 32; ++ci) p += vcol[px][ci];
        p = fmaf(p, 0.03125f, bsv);
        float n2 = p * p;
        n2 += __shfl_xor(n2, 1); n2 += __shfl_xor(n2, 2); n2 += __shfl_xor(n2, 4);
        act[px] = p * n2 * __builtin_amdgcn_rcpf(1.f + n2) * __builtin_amdgcn_rsqf(n2 + 1e-9f);

        float a[8];
#pragma unroll
        for (int j = 0; j < 8; ++j) a[j] = __shfl(act[px], lbase | j);
        float (*lgp)[37] = px ? lg1 : lg0;
#pragma unroll
        for (int q = 0; q < 4; ++q) {
            f32x4 v0 = vr[px][q][0], v1 = vr[px][q][1];
            float d = v0.x * a[0] + v0.y * a[1] + v0.z * a[2] + v0.w * a[3]
                    + v1.x * a[4] + v1.y * a[5] + v1.z * a[6] + v1.w * a[7];
            dlog[px][q] = d;
            lgp[no * 4 + q][co] = d;
        }
    }
    __syncthreads();                                    // (4) logits -> softmax

    // iters 2..3
#pragma unroll
    for (int it = 1; it < 3; ++it) {
#pragma unroll
        for (int px = 0; px < 2; ++px) {                // softmax over co per ci-row
            float (*lgp)[37] = px ? lg1 : lg0;
            float* rtp = px ? route1 : route0;
            float l0 = lgp[co][no],      l1 = lgp[co][no + 8];
            float l2 = lgp[co][no + 16], l3 = lgp[co][no + 24];
            float m = fmaxf(fmaxf(l0, l1), fmaxf(l2, l3));
            m = fmaxf(m, __shfl_xor(m, 1)); m = fmaxf(m, __shfl_xor(m, 2)); m = fmaxf(m, __shfl_xor(m, 4));
            float e0 = __expf(l0 - m), e1 = __expf(l1 - m);
            float e2 = __expf(l2 - m), e3 = __expf(l3 - m);
            float s = e0 + e1 + e2 + e3;
            s += __shfl_xor(s, 1); s += __shfl_xor(s, 2); s += __shfl_xor(s, 4);
            float inv = __builtin_amdgcn_rcpf(s);
            rtp[(no)      * 36 + co] = e0 * inv;
            rtp[(no + 8)  * 36 + co] = e1 * inv;
            rtp[(no + 16) * 36 + co] = e2 * inv;
            rtp[(no + 24) * 36 + co] = e3 * inv;
        }
        __syncthreads();                                // (5/7) route -> preact

#pragma unroll
        for (int px = 0; px < 2; ++px) {
            float* rtp = px ? route1 : route0;
            float p = bsv;
#pragma unroll
            for (int j = 0; j < 8; ++j) {
                f32x4 rv = *(const f32x4*)&rtp[co * 36 + j * 4];
                p = fmaf(rv.x, vcol[px][j * 4 + 0], p);
                p = fmaf(rv.y, vcol[px][j * 4 + 1], p);
                p = fmaf(rv.z, vcol[px][j * 4 + 2], p);
                p = fmaf(rv.w, vcol[px][j * 4 + 3], p);
            }
            float n2 = p * p;
            n2 += __shfl_xor(n2, 1); n2 += __shfl_xor(n2, 2); n2 += __shfl_xor(n2, 4);
            act[px] = p * n2 * __builtin_amdgcn_rcpf(1.f + n2) * __builtin_amdgcn_rsqf(n2 + 1e-9f);

            if (it == 1) {                              // distances via shuffled act
                float a[8];
#pragma unroll
                for (int j = 0; j < 8; ++j) a[j] = __shfl(act[px], lbase | j);
                float (*lgp)[37] = px ? lg1 : lg0;
#pragma unroll
                for (int q = 0; q < 4; ++q) {
                    f32x4 v0 = vr[px][q][0], v1 = vr[px][q][1];
                    float d = v0.x * a[0] + v0.y * a[1] + v0.z * a[2] + v0.w * a[3]
                            + v1.x * a[4] + v1.y * a[5] + v1.z * a[6] + v1.w * a[7];
                    dlog[px][q] += d;
                    lgp[no * 4 + q][co] = dlog[px][q];
                }
            }
        }
        if (it == 1) __syncthreads();                   // (6) logits -> softmax
    }

    // ---- out[b][oc=t][h][w0..w0+1]: one float2 store ----
    float2 o2 = make_float2(act[0], act[1]);
    *(float2*)&out[(b * 256 + t) * 400 + h * 20 + w0] = o2;
}

extern "C" void kernel_launch(void* const* d_in, const int* in_sizes, int n_in,
                              void* d_out, int out_size, void* d_ws, size_t ws_size,
                              hipStream_t stream) {
    const float* x    = (const float*)d_in[0];
    const float* Wt   = (const float*)d_in[1];
    const float* bias = (const float*)d_in[2];
    float* out        = (float*)d_out;
    __bf16* bp        = (__bf16*)d_ws;

    prepack_w_kernel<<<dim3(96), dim3(256), 0, stream>>>(Wt, bp);
    caps_mfma7_kernel<<<dim3(3200), dim3(256), 0, stream>>>(x, bp, bias, out);
}

// Round 9
// 59.723 us; speedup vs baseline: 3.5056x; 1.2114x over previous
//
#include <hip/hip_runtime.h>

#define HH 20
#define WW 20

typedef _Float16 f16x8 __attribute__((ext_vector_type(8)));
typedef float    f32x4  __attribute__((ext_vector_type(4)));
typedef float    f32x4u __attribute__((ext_vector_type(4), aligned(4)));

// ---- prepack W -> fp16, k' = r*8 + ni reorder, K padded 72->96 ----
// ws: B[256][96] _Float16 (49152 B)
__global__ void prepack_w_kernel(const float* __restrict__ Wt, _Float16* __restrict__ bp) {
    int idx = blockIdx.x * 256 + threadIdx.x;     // 24576 total
    int oc = idx / 96, k = idx % 96;
    int r = k >> 3, ni = k & 7;
    float v = (r < 9) ? Wt[oc * 72 + ni * 9 + r] : 0.f;
    bp[idx] = (_Float16)v;
}

// Staging helper: DS = dshift (block-uniform). Window cols w0-1..w0+2 via one f32x4.
template<int DS>
__device__ __forceinline__ void stage_seg(const float* __restrict__ x,
                                          _Float16* A,
                                          int b, int h, int w0, int t) {
#pragma unroll
    for (int s = t; s < 768; s += 256) {               // (ci, ni, hr)
        int ci = s / 24;
        int r  = s % 24;
        int ni = r / 3, hr = r % 3;
        int hh = h - 1 + hr;
        bool hok = (hh >= 0) && (hh < HH);
        const int wlo = (DS == 0) ? (w0 - 1) : (DS < 0 ? 0 : WW - 4);
        const float* rowp = x + ((((b * 32 + ci) * 8 + ni) * HH + (hok ? hh : 0)) * WW) + wlo;
        f32x4u f4 = *(const f32x4u*)rowp;
        float vals[4];
        if (DS == 0)      { vals[0] = f4.x; vals[1] = f4.y; vals[2] = f4.z; vals[3] = f4.w; }
        else if (DS < 0)  { vals[0] = 0.f;  vals[1] = f4.x; vals[2] = f4.y; vals[3] = f4.z; }
        else              { vals[0] = f4.y; vals[1] = f4.z; vals[2] = f4.w; vals[3] = 0.f; }
        int kb = hr * 24 + ni;
#pragma unroll
        for (int j = 0; j < 4; ++j) {                  // window col c = w0-1+j
            float v = hok ? vals[j] : 0.f;
            _Float16 hv = (_Float16)v;
            if (j < 3)                                 // px0, kw=j
                A[ci * 96 + kb + j * 8] = hv;
            if (j > 0)                                 // px1, kw=j-1
                A[(32 + ci) * 96 + kb + (j - 1) * 8] = hv;
        }
    }
}

// ---- fused conv + routing, TWO adjacent pixels per block, fp16 single-term conv ----
// LDS region (30976 B), disjoint this time:
//   A[64][96] fp16 @0 (12288 B)                      [live: stage+conv]
//   wave bufs f32[32][36] @12288 + wv*4608 (18432 B) [live: transpose; wave-private]
//   routing (overlaps bufs, after barrier): route0/1 [32][36] @12288/+4608,
//           lg0/lg1 [32][37] @+9216/+13952 (ends 18688 B into region)
// 6 barriers (was 7): conv->transpose needs none (disjoint + wave-private bufs).
__global__ __launch_bounds__(256, 3)
void caps_mfma8_kernel(const float* __restrict__ x,
                       const _Float16* __restrict__ bp,
                       const float* __restrict__ bias,
                       float* __restrict__ out) {
    __shared__ __align__(16) unsigned char region[30976];
    _Float16* A    = (_Float16*)region;                 // [64][96]
    float* bufbase = (float*)(region + 12288);

    const int t  = threadIdx.x;
    const int wv = t >> 6;
    const int lr = t & 15;
    const int lg = (t >> 4) & 3;

    const int bi  = blockIdx.x;            // 3200 blocks
    const int b   = bi / 200;
    const int rem = bi % 200;
    const int h   = rem / 10;
    const int w0  = (rem % 10) * 2;

    // ---- zero k' pad [72,96): 64 rows * 12 u32 ----
#pragma unroll
    for (int e = t; e < 768; e += 256) {
        int row = e / 12, j = e % 12;
        ((unsigned int*)(A + row * 96 + 72))[j] = 0u;
    }

    // ---- stage x window (block-uniform dshift branch) ----
    const int dshift = (w0 == 0) ? -1 : (w0 == WW - 2) ? 1 : 0;
    if (dshift == 0)      stage_seg<0>(x, A, b, h, w0, t);
    else if (dshift < 0)  stage_seg<-1>(x, A, b, h, w0, t);
    else                  stage_seg<1>(x, A, b, h, w0, t);
    __syncthreads();                                    // (1) stage -> conv

    // ---- conv via fp16 MFMA: M=64, N=256, K=96, single term ----
    f32x4 acc[4][4];                                    // [N-tile i][mt = px*2+half]
#pragma unroll
    for (int i = 0; i < 4; ++i)
#pragma unroll
        for (int mt = 0; mt < 4; ++mt) acc[i][mt] = (f32x4){0.f, 0.f, 0.f, 0.f};

#pragma unroll
    for (int mh = 0; mh < 2; ++mh) {                    // pixel
#pragma unroll
        for (int kst = 0; kst < 3; ++kst) {
            const int kb = kst * 32 + lg * 8;
            f16x8 a0 = *(const f16x8*)&A[(mh * 32 + lr) * 96 + kb];
            f16x8 a1 = *(const f16x8*)&A[(mh * 32 + 16 + lr) * 96 + kb];
#pragma unroll
            for (int i = 0; i < 4; ++i) {
                const int oc = (wv * 4 + i) * 16 + lr;
                f16x8 bv = *(const f16x8*)&bp[oc * 96 + kb];
                acc[i][mh*2+0] = __builtin_amdgcn_mfma_f32_16x16x32_f16(a0, bv, acc[i][mh*2+0], 0, 0, 0);
                acc[i][mh*2+1] = __builtin_amdgcn_mfma_f32_16x16x32_f16(a1, bv, acc[i][mh*2+1], 0, 0, 0);
            }
        }
    }
    // NO barrier: bufs are disjoint from A and wave-private.

    // ---- wave-local transpose: 4 sub-rounds, no barriers ----
    float* buf = bufbase + wv * 1152;                   // f32[32][36]
    float vcol[2][32];                                  // [px][ci] for oc = t
    f32x4 vr[2][4][2];                                  // [px][q] votes[(t&7)*4+q][(t&~7)+0..7]
    const int ch_t = (t >> 5) & 1;
    const int colr = t & 31;
    const int c8   = t & 24;

#pragma unroll
    for (int p = 0; p < 2; ++p) {
#pragma unroll
        for (int ch = 0; ch < 2; ++ch) {
#pragma unroll
            for (int ii = 0; ii < 2; ++ii) {
#pragma unroll
                for (int mm = 0; mm < 2; ++mm) {
#pragma unroll
                    for (int r = 0; r < 4; ++r)
                        buf[(mm * 16 + lg * 4 + r) * 36 + ii * 16 + lr] =
                            acc[ch * 2 + ii][p * 2 + mm][r];
                }
            }
            if (ch_t == ch) {
#pragma unroll
                for (int ci = 0; ci < 32; ++ci) vcol[p][ci] = buf[ci * 36 + colr];
#pragma unroll
                for (int q = 0; q < 4; ++q) {
                    int ciq = (t & 7) * 4 + q;
                    vr[p][q][0] = *(const f32x4*)&buf[ciq * 36 + c8];
                    vr[p][q][1] = *(const f32x4*)&buf[ciq * 36 + c8 + 4];
                }
            }
        }
    }

    // ---- routing: thread owns oc=t (co=t>>3, no=t&7) for BOTH pixels ----
    const int co = t >> 3;
    const int no = t & 7;
    const float bsv = bias[t];
    float* route0 = bufbase;                            // [32][36]
    float* route1 = bufbase + 1152;
    float (*lg0)[37] = (float (*)[37])(bufbase + 2304);
    float (*lg1)[37] = (float (*)[37])(bufbase + 2304 + 1184);
    float dlog[2][4];
    float act[2];
    const int lbase = t & 56;                           // lane base of 8-lane co-group

    // iter 1 (route exactly uniform): all in registers, no LDS
#pragma unroll
    for (int px = 0; px < 2; ++px) {
        float p = 0.f;
#pragma unroll
        for (int ci = 0; ci < 32; ++ci) p += vcol[px][ci];
        p = fmaf(p, 0.03125f, bsv);
        float n2 = p * p;
        n2 += __shfl_xor(n2, 1); n2 += __shfl_xor(n2, 2); n2 += __shfl_xor(n2, 4);
        act[px] = p * n2 * __builtin_amdgcn_rcpf(1.f + n2) * __builtin_amdgcn_rsqf(n2 + 1e-9f);

        float a[8];
#pragma unroll
        for (int j = 0; j < 8; ++j) a[j] = __shfl(act[px], lbase | j);
#pragma unroll
        for (int q = 0; q < 4; ++q) {
            f32x4 v0 = vr[px][q][0], v1 = vr[px][q][1];
            dlog[px][q] = v0.x * a[0] + v0.y * a[1] + v0.z * a[2] + v0.w * a[3]
                        + v1.x * a[4] + v1.y * a[5] + v1.z * a[6] + v1.w * a[7];
        }
    }
    __syncthreads();                                    // (2) all bufs read -> routing region
#pragma unroll
    for (int px = 0; px < 2; ++px) {
        float (*lgp)[37] = px ? lg1 : lg0;
#pragma unroll
        for (int q = 0; q < 4; ++q) lgp[no * 4 + q][co] = dlog[px][q];
    }
    __syncthreads();                                    // (3) logits -> softmax

    // iters 2..3
#pragma unroll
    for (int it = 1; it < 3; ++it) {
#pragma unroll
        for (int px = 0; px < 2; ++px) {                // softmax over co per ci-row
            float (*lgp)[37] = px ? lg1 : lg0;
            float* rtp = px ? route1 : route0;
            float l0 = lgp[co][no],      l1 = lgp[co][no + 8];
            float l2 = lgp[co][no + 16], l3 = lgp[co][no + 24];
            float m = fmaxf(fmaxf(l0, l1), fmaxf(l2, l3));
            m = fmaxf(m, __shfl_xor(m, 1)); m = fmaxf(m, __shfl_xor(m, 2)); m = fmaxf(m, __shfl_xor(m, 4));
            float e0 = __expf(l0 - m), e1 = __expf(l1 - m);
            float e2 = __expf(l2 - m), e3 = __expf(l3 - m);
            float s = e0 + e1 + e2 + e3;
            s += __shfl_xor(s, 1); s += __shfl_xor(s, 2); s += __shfl_xor(s, 4);
            float inv = __builtin_amdgcn_rcpf(s);
            rtp[(no)      * 36 + co] = e0 * inv;
            rtp[(no + 8)  * 36 + co] = e1 * inv;
            rtp[(no + 16) * 36 + co] = e2 * inv;
            rtp[(no + 24) * 36 + co] = e3 * inv;
        }
        __syncthreads();                                // (4/6) route -> preact

#pragma unroll
        for (int px = 0; px < 2; ++px) {
            float* rtp = px ? route1 : route0;
            float p = bsv;
#pragma unroll
            for (int j = 0; j < 8; ++j) {
                f32x4 rv = *(const f32x4*)&rtp[co * 36 + j * 4];
                p = fmaf(rv.x, vcol[px][j * 4 + 0], p);
                p = fmaf(rv.y, vcol[px][j * 4 + 1], p);
                p = fmaf(rv.z, vcol[px][j * 4 + 2], p);
                p = fmaf(rv.w, vcol[px][j * 4 + 3], p);
            }
            float n2 = p * p;
            n2 += __shfl_xor(n2, 1); n2 += __shfl_xor(n2, 2); n2 += __shfl_xor(n2, 4);
            act[px] = p * n2 * __builtin_amdgcn_rcpf(1.f + n2) * __builtin_amdgcn_rsqf(n2 + 1e-9f);

            if (it == 1) {                              // distances via shuffled act
                float a[8];
#pragma unroll
                for (int j = 0; j < 8; ++j) a[j] = __shfl(act[px], lbase | j);
                float (*lgp)[37] = px ? lg1 : lg0;
#pragma unroll
                for (int q = 0; q < 4; ++q) {
                    f32x4 v0 = vr[px][q][0], v1 = vr[px][q][1];
                    float d = v0.x * a[0] + v0.y * a[1] + v0.z * a[2] + v0.w * a[3]
                            + v1.x * a[4] + v1.y * a[5] + v1.z * a[6] + v1.w * a[7];
                    dlog[px][q] += d;
                    lgp[no * 4 + q][co] = dlog[px][q];
                }
            }
        }
        if (it == 1) __syncthreads();                   // (5) logits -> softmax
    }

    // ---- out[b][oc=t][h][w0..w0+1]: one float2 store ----
    float2 o2 = make_float2(act[0], act[1]);
    *(float2*)&out[(b * 256 + t) * 400 + h * 20 + w0] = o2;
}

extern "C" void kernel_launch(void* const* d_in, const int* in_sizes, int n_in,
                              void* d_out, int out_size, void* d_ws, size_t ws_size,
                              hipStream_t stream) {
    const float* x    = (const float*)d_in[0];
    const float* Wt   = (const float*)d_in[1];
    const float* bias = (const float*)d_in[2];
    float* out        = (float*)d_out;
    _Float16* bp      = (_Float16*)d_ws;

    prepack_w_kernel<<<dim3(96), dim3(256), 0, stream>>>(Wt, bp);
    caps_mfma8_kernel<<<dim3(3200), dim3(256), 0, stream>>>(x, bp, bias, out);
}

// Round 10
// 54.851 us; speedup vs baseline: 3.8170x; 1.0888x over previous
//
#include <hip/hip_runtime.h>

#define HH 20
#define WW 20

typedef _Float16 f16x8 __attribute__((ext_vector_type(8)));
typedef float    f32x4  __attribute__((ext_vector_type(4)));
typedef float    f32x4u __attribute__((ext_vector_type(4), aligned(4)));

// ---- prepack W -> fp16, k' = r*8 + ni reorder, K padded 72->96 ----
__global__ void prepack_w_kernel(const float* __restrict__ Wt, _Float16* __restrict__ bp) {
    int idx = blockIdx.x * 256 + threadIdx.x;     // 24576 total
    int oc = idx / 96, k = idx % 96;
    int r = k >> 3, ni = k & 7;
    float v = (r < 9) ? Wt[oc * 72 + ni * 9 + r] : 0.f;
    bp[idx] = (_Float16)v;
}

// Staging helper: DS = dshift (block-uniform).
template<int DS>
__device__ __forceinline__ void stage_seg(const float* __restrict__ x,
                                          _Float16* A,
                                          int b, int h, int w0, int t) {
#pragma unroll
    for (int s = t; s < 768; s += 256) {               // (ci, ni, hr)
        int ci = s / 24;
        int r  = s % 24;
        int ni = r / 3, hr = r % 3;
        int hh = h - 1 + hr;
        bool hok = (hh >= 0) && (hh < HH);
        const int wlo = (DS == 0) ? (w0 - 1) : (DS < 0 ? 0 : WW - 4);
        const float* rowp = x + ((((b * 32 + ci) * 8 + ni) * HH + (hok ? hh : 0)) * WW) + wlo;
        f32x4u f4 = *(const f32x4u*)rowp;
        float vals[4];
        if (DS == 0)      { vals[0] = f4.x; vals[1] = f4.y; vals[2] = f4.z; vals[3] = f4.w; }
        else if (DS < 0)  { vals[0] = 0.f;  vals[1] = f4.x; vals[2] = f4.y; vals[3] = f4.z; }
        else              { vals[0] = f4.y; vals[1] = f4.z; vals[2] = f4.w; vals[3] = 0.f; }
        int kb = hr * 24 + ni;
#pragma unroll
        for (int j = 0; j < 4; ++j) {                  // window col c = w0-1+j
            float v = hok ? vals[j] : 0.f;
            _Float16 hv = (_Float16)v;
            if (j < 3)  A[ci * 96 + kb + j * 8] = hv;            // px0
            if (j > 0)  A[(32 + ci) * 96 + kb + (j - 1) * 8] = hv; // px1
        }
    }
}

// Butterfly transpose-reduce over the 8-lane group: v[j] = partial for slot j;
// returns Sum_lanes v[lane&7] on each lane (its own slot). All indices static.
__device__ __forceinline__ float bfly8(const float v[8], int lane) {
    const bool b0 = lane & 1, b1 = lane & 2, b2 = lane & 4;
    float k0 = b0 ? v[1] : v[0], s0 = b0 ? v[0] : v[1];
    float k1 = b0 ? v[3] : v[2], s1 = b0 ? v[2] : v[3];
    float k2 = b0 ? v[5] : v[4], s2 = b0 ? v[4] : v[5];
    float k3 = b0 ? v[7] : v[6], s3 = b0 ? v[6] : v[7];
    k0 += __shfl_xor(s0, 1); k1 += __shfl_xor(s1, 1);
    k2 += __shfl_xor(s2, 1); k3 += __shfl_xor(s3, 1);
    float m0 = b1 ? k1 : k0, t0 = b1 ? k0 : k1;
    float m1 = b1 ? k3 : k2, t1 = b1 ? k2 : k3;
    m0 += __shfl_xor(t0, 2); m1 += __shfl_xor(t1, 2);
    float r0 = b2 ? m1 : m0, r1 = b2 ? m0 : m1;
    return r0 + __shfl_xor(r1, 4);
}

// ---- fused conv + routing, 2 pixels/block, fp16 conv, vr-only routing ----
// LDS region (30976 B):
//   A[64][96] fp16 @0 (12288 B)                      [stage+conv]
//   wave bufs f32[32][36] @12288 + wv*4608 (18432 B) [transpose; wave-private]
//   routing overlays bufs: route0/1 [co][ci] @+0/+1152, lg0/1 [ci][37] @+2304/+3488 (f32 idx)
__global__ __launch_bounds__(256, 4)
void caps_mfma9_kernel(const float* __restrict__ x,
                       const _Float16* __restrict__ bp,
                       const float* __restrict__ bias,
                       float* __restrict__ out) {
    __shared__ __align__(16) unsigned char region[30976];
    _Float16* A    = (_Float16*)region;                 // [64][96]
    float* bufbase = (float*)(region + 12288);

    const int t  = threadIdx.x;
    const int wv = t >> 6;
    const int lr = t & 15;
    const int lg = (t >> 4) & 3;

    const int bi  = blockIdx.x;            // 3200 blocks
    const int b   = bi / 200;
    const int rem = bi % 200;
    const int h   = rem / 10;
    const int w0  = (rem % 10) * 2;

    // ---- zero k' pad [72,96) ----
#pragma unroll
    for (int e = t; e < 768; e += 256) {
        int row = e / 12, j = e % 12;
        ((unsigned int*)(A + row * 96 + 72))[j] = 0u;
    }

    // ---- stage x window ----
    const int dshift = (w0 == 0) ? -1 : (w0 == WW - 2) ? 1 : 0;
    if (dshift == 0)      stage_seg<0>(x, A, b, h, w0, t);
    else if (dshift < 0)  stage_seg<-1>(x, A, b, h, w0, t);
    else                  stage_seg<1>(x, A, b, h, w0, t);
    __syncthreads();                                    // (1) stage -> conv

    // ---- conv via fp16 MFMA: M=64, N=256, K=96; B loaded once per (kst,i) ----
    f32x4 acc[4][4];                                    // [N-tile i][mt = px*2 + rowhalf]
#pragma unroll
    for (int i = 0; i < 4; ++i)
#pragma unroll
        for (int mt = 0; mt < 4; ++mt) acc[i][mt] = (f32x4){0.f, 0.f, 0.f, 0.f};

#pragma unroll
    for (int kst = 0; kst < 3; ++kst) {
        const int kb = kst * 32 + lg * 8;
        f16x8 af0 = *(const f16x8*)&A[(lr)      * 96 + kb];   // px0 rows 0-15
        f16x8 af1 = *(const f16x8*)&A[(16 + lr) * 96 + kb];   // px0 rows 16-31
        f16x8 af2 = *(const f16x8*)&A[(32 + lr) * 96 + kb];   // px1 rows 0-15
        f16x8 af3 = *(const f16x8*)&A[(48 + lr) * 96 + kb];   // px1 rows 16-31
#pragma unroll
        for (int i = 0; i < 4; ++i) {
            const int oc = (wv * 4 + i) * 16 + lr;
            f16x8 bv = *(const f16x8*)&bp[oc * 96 + kb];
            acc[i][0] = __builtin_amdgcn_mfma_f32_16x16x32_f16(af0, bv, acc[i][0], 0, 0, 0);
            acc[i][1] = __builtin_amdgcn_mfma_f32_16x16x32_f16(af1, bv, acc[i][1], 0, 0, 0);
            acc[i][2] = __builtin_amdgcn_mfma_f32_16x16x32_f16(af2, bv, acc[i][2], 0, 0, 0);
            acc[i][3] = __builtin_amdgcn_mfma_f32_16x16x32_f16(af3, bv, acc[i][3], 0, 0, 0);
        }
    }
    // NO barrier: wave bufs disjoint from A and wave-private.

    // ---- wave-local transpose -> vr only (vcol eliminated) ----
    float* buf = bufbase + wv * 1152;                   // f32[32][36]
    f32x4 vr[2][4][2];                                  // [px][q]: votes[(t&7)*4+q][(t&~7)+0..7]
    const int ch_t = (t >> 5) & 1;
    const int c8   = t & 24;

#pragma unroll
    for (int p = 0; p < 2; ++p) {
#pragma unroll
        for (int ch = 0; ch < 2; ++ch) {
#pragma unroll
            for (int ii = 0; ii < 2; ++ii) {
#pragma unroll
                for (int mm = 0; mm < 2; ++mm) {
#pragma unroll
                    for (int r = 0; r < 4; ++r)
                        buf[(mm * 16 + lg * 4 + r) * 36 + ii * 16 + lr] =
                            acc[ch * 2 + ii][p * 2 + mm][r];
                }
            }
            if (ch_t == ch) {
#pragma unroll
                for (int q = 0; q < 4; ++q) {
                    int ciq = (t & 7) * 4 + q;
                    vr[p][q][0] = *(const f32x4*)&buf[ciq * 36 + c8];
                    vr[p][q][1] = *(const f32x4*)&buf[ciq * 36 + c8 + 4];
                }
            }
        }
    }

    // ---- routing: thread owns oc=t (co=t>>3, no=t&7) for BOTH pixels ----
    const int co = t >> 3;
    const int no = t & 7;
    const float bsv = bias[t];
    float* route0 = bufbase;                            // route_T[co][ci], [32][36]
    float* route1 = bufbase + 1152;
    float (*lg0)[37] = (float (*)[37])(bufbase + 2304); // logits[ci][co]
    float (*lg1)[37] = (float (*)[37])(bufbase + 2304 + 1184);
    float dlog[2][4];
    float act[2];
    const int lbase = t & 56;

    // iter 1 (uniform route): preact via q-sum + butterfly, all registers
#pragma unroll
    for (int px = 0; px < 2; ++px) {
        float pj[8];
#pragma unroll
        for (int j = 0; j < 4; ++j) {
            pj[j]     = vr[px][0][0][j] + vr[px][1][0][j] + vr[px][2][0][j] + vr[px][3][0][j];
            pj[4 + j] = vr[px][0][1][j] + vr[px][1][1][j] + vr[px][2][1][j] + vr[px][3][1][j];
        }
        float p = fmaf(bfly8(pj, t), 0.03125f, bsv);
        float n2 = p * p;
        n2 += __shfl_xor(n2, 1); n2 += __shfl_xor(n2, 2); n2 += __shfl_xor(n2, 4);
        act[px] = p * n2 * __builtin_amdgcn_rcpf(1.f + n2) * __builtin_amdgcn_rsqf(n2 + 1e-9f);

        float a[8];
#pragma unroll
        for (int j = 0; j < 8; ++j) a[j] = __shfl(act[px], lbase | j);
#pragma unroll
        for (int q = 0; q < 4; ++q) {
            f32x4 v0 = vr[px][q][0], v1 = vr[px][q][1];
            dlog[px][q] = v0.x * a[0] + v0.y * a[1] + v0.z * a[2] + v0.w * a[3]
                        + v1.x * a[4] + v1.y * a[5] + v1.z * a[6] + v1.w * a[7];
        }
    }
    __syncthreads();                                    // (2) all bufs read -> overlay routing
#pragma unroll
    for (int px = 0; px < 2; ++px) {
        float (*lgp)[37] = px ? lg1 : lg0;
#pragma unroll
        for (int q = 0; q < 4; ++q) lgp[no * 4 + q][co] = dlog[px][q];
    }
    __syncthreads();                                    // (3) logits -> softmax

    // iters 2..3
#pragma unroll
    for (int it = 1; it < 3; ++it) {
#pragma unroll
        for (int px = 0; px < 2; ++px) {                // softmax over co per ci-row (row = t>>3)
            float (*lgp)[37] = px ? lg1 : lg0;
            float* rtp = px ? route1 : route0;
            float l0 = lgp[co][no],      l1 = lgp[co][no + 8];
            float l2 = lgp[co][no + 16], l3 = lgp[co][no + 24];
            float m = fmaxf(fmaxf(l0, l1), fmaxf(l2, l3));
            m = fmaxf(m, __shfl_xor(m, 1)); m = fmaxf(m, __shfl_xor(m, 2)); m = fmaxf(m, __shfl_xor(m, 4));
            float e0 = __expf(l0 - m), e1 = __expf(l1 - m);
            float e2 = __expf(l2 - m), e3 = __expf(l3 - m);
            float s = e0 + e1 + e2 + e3;
            s += __shfl_xor(s, 1); s += __shfl_xor(s, 2); s += __shfl_xor(s, 4);
            float inv = __builtin_amdgcn_rcpf(s);
            rtp[(no)      * 36 + co] = e0 * inv;
            rtp[(no + 8)  * 36 + co] = e1 * inv;
            rtp[(no + 16) * 36 + co] = e2 * inv;
            rtp[(no + 24) * 36 + co] = e3 * inv;
        }
        __syncthreads();                                // (4/6) route -> preact

#pragma unroll
        for (int px = 0; px < 2; ++px) {
            float* rtp = px ? route1 : route0;
            f32x4 rv = *(const f32x4*)&rtp[co * 36 + (t & 7) * 4];  // route_T[co][4 ci's]
            float pj[8];
#pragma unroll
            for (int j = 0; j < 4; ++j) {
                pj[j]     = rv.x * vr[px][0][0][j] + rv.y * vr[px][1][0][j]
                          + rv.z * vr[px][2][0][j] + rv.w * vr[px][3][0][j];
                pj[4 + j] = rv.x * vr[px][0][1][j] + rv.y * vr[px][1][1][j]
                          + rv.z * vr[px][2][1][j] + rv.w * vr[px][3][1][j];
            }
            float p = bsv + bfly8(pj, t);
            float n2 = p * p;
            n2 += __shfl_xor(n2, 1); n2 += __shfl_xor(n2, 2); n2 += __shfl_xor(n2, 4);
            act[px] = p * n2 * __builtin_amdgcn_rcpf(1.f + n2) * __builtin_amdgcn_rsqf(n2 + 1e-9f);

            if (it == 1) {                              // distances via shuffled act
                float a[8];
#pragma unroll
                for (int j = 0; j < 8; ++j) a[j] = __shfl(act[px], lbase | j);
                float (*lgp)[37] = px ? lg1 : lg0;
#pragma unroll
                for (int q = 0; q < 4; ++q) {
                    f32x4 v0 = vr[px][q][0], v1 = vr[px][q][1];
                    float d = v0.x * a[0] + v0.y * a[1] + v0.z * a[2] + v0.w * a[3]
                            + v1.x * a[4] + v1.y * a[5] + v1.z * a[6] + v1.w * a[7];
                    dlog[px][q] += d;
                    lgp[no * 4 + q][co] = dlog[px][q];
                }
            }
        }
        if (it == 1) __syncthreads();                   // (5) logits -> softmax
    }

    // ---- out[b][oc=t][h][w0..w0+1] ----
    float2 o2 = make_float2(act[0], act[1]);
    *(float2*)&out[(b * 256 + t) * 400 + h * 20 + w0] = o2;
}

extern "C" void kernel_launch(void* const* d_in, const int* in_sizes, int n_in,
                              void* d_out, int out_size, void* d_ws, size_t ws_size,
                              hipStream_t stream) {
    const float* x    = (const float*)d_in[0];
    const float* Wt   = (const float*)d_in[1];
    const float* bias = (const float*)d_in[2];
    float* out        = (float*)d_out;
    _Float16* bp      = (_Float16*)d_ws;

    prepack_w_kernel<<<dim3(96), dim3(256), 0, stream>>>(Wt, bp);
    caps_mfma9_kernel<<<dim3(3200), dim3(256), 0, stream>>>(x, bp, bias, out);
}